// Round 1
// 1314.227 us; speedup vs baseline: 1.0184x; 1.0184x over previous
//
#include <hip/hip_runtime.h>

// RandomPooling2D: out[b,c,i,j] = x[b,c, 2*i + pick_i, 2*j + pick_j]
// B=16, C=64, H=W=512, OH=OW=256, stride=2, kernel=2 (pick_* in {0,1}).
//
// Layout constants (all powers of two):
//   W  = 512  (input row, floats)      H*W = 2^18 floats
//   OH = 256, OW = 256, OW/4 = 64      total out float4 groups = 2^24
//
// v2: persistent grid-stride kernel.
//   Previous version launched 65,536 short-lived workgroups (262,144 waves,
//   each: 2 loads + 1 store, then die) -> workgroup-dispatch / latency bound
//   at ~1.2 TB/s effective. This version launches 2048 blocks (8/CU, fully
//   resident at VGPR=8), each thread producing 32 float4 outputs.
//
//   Grid-stride trick: stride = 2048*256 = 2^19 float4 groups. For
//   n = t + k*2^19:  j4 = n&63 and i = (n>>6)&255 are INVARIANT in k
//   (2^19 only touches bits >= 19; j4 uses bits 0..5, i uses bits 6..13),
//   only bc = n>>14 advances by 32 per iteration. So the inner loop is just
//   "advance base by 32 bc-planes, 2 loads, 1 store" — no index recompute.
//
//   Each lane still covers a contiguous 32 B of input per iteration (the two
//   dwordx4 loads of a wave interleave to a dense 2 KB row chunk), and each
//   grid-iteration k covers a contiguous 8 MB output / 32 MB input region.

__global__ __launch_bounds__(256, 8) void RandomPooling2D_kernel(
    const float* __restrict__ x,
    const int* __restrict__ p_pick_i,
    const int* __restrict__ p_pick_j,
    float4* __restrict__ out)
{
    const int t = blockIdx.x * blockDim.x + threadIdx.x;   // 0 .. 2^19-1

    const int pick_i = *p_pick_i;   // uniform scalar loads (hoisted)
    const int pick_j = *p_pick_j;

    const int j4  = t & 63;          // output column group (constant over k)
    const int i   = (t >> 6) & 255;  // output row          (constant over k)
    const int bc0 = t >> 14;         // starting batch*channel plane (0..31)

    // input offset in floats: bc0*2^18 + (2i+pick_i)*512 + 8*j4  (32B aligned)
    const size_t base = ((size_t)bc0 << 18)
                      + ((size_t)((i << 1) + pick_i) << 9)
                      + ((size_t)j4 << 3);
    const float* p = x + base;

    // 32 iterations: bc = bc0 + 32*k, k = 0..31. Input advances 2^23 floats
    // (32 bc-planes) per iteration; output advances 2^19 float4 groups.
    if (pick_j == 0) {               // wave-uniform branch hoisted out of loop
        #pragma unroll 8
        for (int k = 0; k < 32; ++k) {
            const float4 a = *(const float4*)(p + ((size_t)k << 23));
            const float4 b = *(const float4*)(p + ((size_t)k << 23) + 4);
            float4 o;
            o.x = a.x; o.y = a.z; o.z = b.x; o.w = b.z;   // even columns
            out[t + (k << 19)] = o;
        }
    } else {
        #pragma unroll 8
        for (int k = 0; k < 32; ++k) {
            const float4 a = *(const float4*)(p + ((size_t)k << 23));
            const float4 b = *(const float4*)(p + ((size_t)k << 23) + 4);
            float4 o;
            o.x = a.y; o.y = a.w; o.z = b.y; o.w = b.w;   // odd columns
            out[t + (k << 19)] = o;
        }
    }
}

extern "C" void kernel_launch(void* const* d_in, const int* in_sizes, int n_in,
                              void* d_out, int out_size, void* d_ws, size_t ws_size,
                              hipStream_t stream)
{
    const float* x        = (const float*)d_in[0];
    const int*   p_pick_i = (const int*)d_in[1];
    const int*   p_pick_j = (const int*)d_in[2];
    float4*      out      = (float4*)d_out;

    // out_size = 16*64*256*256 = 67,108,864 floats -> 16,777,216 float4 groups.
    // Persistent grid: 2048 blocks (8 per CU on 256 CUs) x 256 threads
    // = 2^19 threads, 32 float4 outputs per thread.
    const int block = 256;
    const int grid  = 2048;

    RandomPooling2D_kernel<<<grid, block, 0, stream>>>(x, p_pick_i, p_pick_j, out);
}